// Round 9
// baseline (129.545 us; speedup 1.0000x reference)
//
#include <hip/hip_runtime.h>

#define NPTS 131072

#define FRAG0_OFF    0
#define FRAG0_BYTES  4096
#define FRAGH_OFF    4096
#define HLAYER_BYTES 32768
#define FRAGH_BYTES  (3 * HLAYER_BYTES)
#define WCHUNKS      100                         // (FRAG0+FRAGH)/1024
#define BIAS_OFF     (FRAGH_OFF + FRAGH_BYTES)   // 102400
#define BIAS_BYTES   2048
#define WO_OFF       (BIAS_OFF + BIAS_BYTES)     // 104448
#define WOBO_BYTES   528
#define MLP_BYTES    (WO_OFF + WOBO_BYTES)       // dp at 0, ic at MLP_BYTES

typedef _Float16 f16;
typedef __attribute__((ext_vector_type(8)))  _Float16 f16x8;
typedef __attribute__((ext_vector_type(16))) float    f32x16;

#define C2LOG2E 2.8853900817779268f   // 2*log2(e), folded into W/b of all layers

// tanh(true_x) where x = C2LOG2E*true_x is the folded pre-activation
__device__ __forceinline__ float tanh2(float x){
  float e = __builtin_amdgcn_exp2f(x);
  return 1.0f - 2.0f * __builtin_amdgcn_rcpf(e + 1.0f);
}

__device__ __forceinline__ void gl_lds16(const void* g, void* l){
  __builtin_amdgcn_global_load_lds(
      (const __attribute__((address_space(1))) void*)g,
      (__attribute__((address_space(3))) void*)l, 16, 0, 0);
}

// ---------------- weight packing (r7 layout, verified: C2LOG2E fold on W,b) ----
__global__ void pack_weights(
    const float* __restrict__ dpW0, const float* __restrict__ dpb0,
    const float* __restrict__ dpWh, const float* __restrict__ dpbh,
    const float* __restrict__ dpWo, const float* __restrict__ dpbo,
    const float* __restrict__ icW0, const float* __restrict__ icb0,
    const float* __restrict__ icWh, const float* __restrict__ icbh,
    const float* __restrict__ icWo, const float* __restrict__ icbo,
    unsigned char* __restrict__ ws)
{
  int tid = blockIdx.x * blockDim.x + threadIdx.x;
  int nth = gridDim.x * blockDim.x;
  for (int m = 0; m < 2; ++m){
    const float* W0 = m ? icW0 : dpW0;
    const float* Wh = m ? icWh : dpWh;
    const float* b0 = m ? icb0 : dpb0;
    const float* bh = m ? icbh : dpbh;
    const float* Wo = m ? icWo : dpWo;
    const float* bo = m ? icbo : dpbo;
    const int indim = m ? 5 : 6;
    unsigned char* base = ws + m * MLP_BYTES;

    f16* dstF0 = (f16*)(base + FRAG0_OFF);
    for (int idx = tid; idx < 2048; idx += nth){
      int e    = idx & 7;
      int lane = (idx >> 3) & 63;
      int jt   = idx >> 9;
      int j = 32*jt + (lane & 31);
      int k = 8*(lane >> 5) + e;
      float v = (k < indim) ? W0[k*128 + j] * C2LOG2E : 0.0f;
      dstF0[idx] = (f16)v;
    }
    f16* dstFH = (f16*)(base + FRAGH_OFF);
    for (int idx = tid; idx < 3*16384; idx += nth){
      int layer = idx / 16384;
      int q     = idx & 16383;
      int e    = q & 7;
      int lane = (q >> 3) & 63;
      int f    = q >> 9;            // f = jt*8 + s
      int jt = f >> 3, s = f & 7;
      int j = 32*jt + (lane & 31);
      int k = 16*s + 8*(lane >> 5) + e;
      int row = (k & ~12) | ((k & 4) << 1) | ((k & 8) >> 1); // sigma: swap bits 2,3
      float v = Wh[(layer*128 + row)*128 + j] * C2LOG2E;
      dstFH[idx] = (f16)v;
    }
    float* dstB = (float*)(base + BIAS_OFF);
    for (int idx = tid; idx < 512; idx += nth)
      dstB[idx] = ((idx < 128) ? b0[idx] : bh[idx - 128]) * C2LOG2E;
    float* dstW = (float*)(base + WO_OFF);
    for (int idx = tid; idx < 128; idx += nth) dstW[idx] = Wo[idx];
    if (tid == 0) dstW[128] = bo[0];
  }
}

// ---------------- main fused kernel ----------------
__device__ __forceinline__ f32x16 load_bias16(const float* bp){
  float4 q0 = *(const float4*)(bp +  0);
  float4 q1 = *(const float4*)(bp +  8);
  float4 q2 = *(const float4*)(bp + 16);
  float4 q3 = *(const float4*)(bp + 24);
  f32x16 a;
  a[0]=q0.x;  a[1]=q0.y;  a[2]=q0.z;  a[3]=q0.w;
  a[4]=q1.x;  a[5]=q1.y;  a[6]=q1.z;  a[7]=q1.w;
  a[8]=q2.x;  a[9]=q2.y;  a[10]=q2.z; a[11]=q2.w;
  a[12]=q3.x; a[13]=q3.y; a[14]=q3.z; a[15]=q3.w;
  return a;
}

// 256 blocks x 1024 threads (16 waves = 4/SIMD). Each wave owns ONE 32-point
// column tile and all 128 rows (acc = 4 x f32x16 = 64 regs). B-frags built in
// registers from own acc (sigma folded into packed weights). Weights LDS-
// resident: stage dp once, run 3 dp chains (zero barriers), restage ic, run ic.
// launch_bounds(1024,4): 4 waves/EU -> 128-VGPR budget (r8's default bound of
// 8 waves/EU forced a 64-VGPR cap -> acc spilled to scratch -> 387 MB HBM).
__global__ __launch_bounds__(1024, 4) void node_main(
    const float* __restrict__ tx,
    const unsigned char* __restrict__ ws,
    float* __restrict__ out)
{
  __shared__ __align__(16) unsigned char sW[FRAG0_BYTES + FRAGH_BYTES]; // 100KB
  __shared__ __align__(16) float sBias[512];
  __shared__ __align__(16) float sWo[136];

  const int tid  = threadIdx.x;
  const int wave = tid >> 6;
  const int lane = tid & 63;
  const int c    = lane & 31;
  const int hi   = lane >> 5;
  const int gp   = blockIdx.x * 512 + wave * 32 + c;

  auto stage = [&](const unsigned char* mb){
    for (int k = wave; k < WCHUNKS; k += 16)
      gl_lds16(mb + k*1024 + lane*16, sW + k*1024);
    for (int i = tid; i < 128; i += 1024)
      ((uint4*)sBias)[i] = ((const uint4*)(mb + BIAS_OFF))[i];
    for (int i = tid; i < 33; i += 1024)
      ((uint4*)sWo)[i] = ((const uint4*)(mb + WO_OFF))[i];
  };

  stage(ws);                       // dp weights -> LDS (issue before feature math)

  // ---- features (hi halves redundant: broadcast loads) ----
  float4 cc = ((const float4*)tx)[gp];
  float x = cc.y, y = cc.z, z = cc.w;
  float xy = x*x + y*y;
  float r    = sqrtf(xy + z*z + 1e-8f);
  float rho  = sqrtf(xy + 1e-8f);
  float rin  = __builtin_amdgcn_rcpf(r);
  float rhin = __builtin_amdgcn_rcpf(rho);
  float u    = r * __builtin_amdgcn_rcpf(1.0f + r);
  float cth  = z * rin;
  float sth  = rho * rin;
  float cph  = x * rhin;
  float sph  = y * rhin;
  float th   = 0.5f * cc.x;     // a = t/2 (t0 = 0)

  float vsum = 0.0f;

  auto run_chain = [&](int chain){
    const float gn = (chain == 0) ? -0.7745966692414834f :
                     (chain == 2) ?  0.7745966692414834f : 0.0f;
    // input B-frag: k-slot = feature index (hi half = zero padding)
    f16x8 b0f;
    #pragma unroll
    for (int e = 0; e < 8; ++e) b0f[e] = (f16)0.0f;
    if (hi == 0){
      if (chain == 3){
        b0f[0]=(f16)u;   b0f[1]=(f16)cth; b0f[2]=(f16)sth;
        b0f[3]=(f16)cph; b0f[4]=(f16)sph;
      } else {
        float ts = th * (1.0f + gn);
        b0f[0]=(f16)ts;  b0f[1]=(f16)u;   b0f[2]=(f16)cth;
        b0f[3]=(f16)sth; b0f[4]=(f16)cph; b0f[5]=(f16)sph;
      }
    }

    f32x16 acc[4];
    // ---- input layer (bias as MFMA C-in) ----
    {
      const f16x8* fr = (const f16x8*)sW;
      #pragma unroll
      for (int jt = 0; jt < 4; ++jt)
        acc[jt] = __builtin_amdgcn_mfma_f32_32x32x16_f16(
                    fr[jt*64 + lane], b0f,
                    load_bias16(&sBias[32*jt + 4*hi]), 0,0,0);
    }

    // ---- 3 hidden layers, weights resident in LDS, B in registers ----
    #pragma unroll 1
    for (int L = 0; L < 3; ++L){
      union { f16x8 v; unsigned uu[4]; } bf[8];
      #pragma unroll
      for (int jt = 0; jt < 4; ++jt)
        #pragma unroll
        for (int cq = 0; cq < 2; ++cq)
          #pragma unroll
          for (int e = 0; e < 4; ++e){
            float t0 = tanh2(acc[jt][8*cq + 2*e]);
            float t1 = tanh2(acc[jt][8*cq + 2*e + 1]);
            auto pk = __builtin_amdgcn_cvt_pkrtz(t0, t1);
            bf[2*jt + cq].uu[e] = __builtin_bit_cast(unsigned, pk);
          }
      const f16x8* fh = (const f16x8*)(sW + FRAGH_OFF + L*HLAYER_BYTES);
      #pragma unroll
      for (int jt = 0; jt < 4; ++jt){
        f32x16 t = load_bias16(&sBias[(L+1)*128 + 32*jt + 4*hi]);
        #pragma unroll
        for (int s = 0; s < 8; ++s)
          t = __builtin_amdgcn_mfma_f32_32x32x16_f16(
                fh[(jt*8 + s)*64 + lane], bf[s].v, t, 0,0,0);
        acc[jt] = t;
      }
    }

    // ---- output layer: v = sum_j tanh(h_j) * Wo[j] + bo ----
    float v = 0.0f;
    #pragma unroll
    for (int jt = 0; jt < 4; ++jt){
      const float* wp = &sWo[32*jt + 4*hi];
      float4 q0 = *(const float4*)(wp +  0);
      float4 q1 = *(const float4*)(wp +  8);
      float4 q2 = *(const float4*)(wp + 16);
      float4 q3 = *(const float4*)(wp + 24);
      f32x16 A = acc[jt];
      v += tanh2(A[0])*q0.x  + tanh2(A[1])*q0.y
         + tanh2(A[2])*q0.z  + tanh2(A[3])*q0.w
         + tanh2(A[4])*q1.x  + tanh2(A[5])*q1.y
         + tanh2(A[6])*q1.z  + tanh2(A[7])*q1.w
         + tanh2(A[8])*q2.x  + tanh2(A[9])*q2.y
         + tanh2(A[10])*q2.z + tanh2(A[11])*q2.w
         + tanh2(A[12])*q3.x + tanh2(A[13])*q3.y
         + tanh2(A[14])*q3.z + tanh2(A[15])*q3.w;
    }
    v += __shfl_xor(v, 32);            // combine the two row-halves
    v += sWo[128];                     // bo
    if (chain == 3) vsum += v;
    else {
      const float wq = (chain == 1) ? 0.8888888888888889f
                                    : 0.5555555555555556f;
      vsum = __builtin_fmaf(th * wq, v, vsum);
    }
  };

  __syncthreads();                 // dp staging visible
  #pragma unroll 1
  for (int chain = 0; chain < 3; ++chain) run_chain(chain);
  __syncthreads();                 // all waves done reading dp weights
  stage(ws + MLP_BYTES);           // ic weights over same LDS
  __syncthreads();
  run_chain(3);

  if (hi == 0) out[gp] = vsum;
}

extern "C" void kernel_launch(void* const* d_in, const int* in_sizes, int n_in,
                              void* d_out, int out_size, void* d_ws, size_t ws_size,
                              hipStream_t stream)
{
  const float* tx = (const float*)d_in[0];
  pack_weights<<<64, 256, 0, stream>>>(
      (const float*)d_in[1],  (const float*)d_in[2],  (const float*)d_in[3],
      (const float*)d_in[4],  (const float*)d_in[5],  (const float*)d_in[6],
      (const float*)d_in[7],  (const float*)d_in[8],  (const float*)d_in[9],
      (const float*)d_in[10], (const float*)d_in[11], (const float*)d_in[12],
      (unsigned char*)d_ws);
  node_main<<<NPTS/512, 1024, 0, stream>>>(tx, (const unsigned char*)d_ws, (float*)d_out);
}

// Round 10
// 129.531 us; speedup vs baseline: 1.0001x; 1.0001x over previous
//
#include <hip/hip_runtime.h>

#define NPTS 131072

#define FRAG0_OFF    0
#define FRAG0_BYTES  4096
#define FRAGH_OFF    4096
#define HLAYER_BYTES 32768
#define FRAGH_BYTES  (3 * HLAYER_BYTES)
#define WCHUNKS      100                         // (FRAG0+FRAGH)/1024
#define BIAS_OFF     (FRAGH_OFF + FRAGH_BYTES)   // 102400
#define BIAS_BYTES   2048
#define WO_OFF       (BIAS_OFF + BIAS_BYTES)     // 104448
#define WOBO_BYTES   528
#define MLP_BYTES    (WO_OFF + WOBO_BYTES)       // dp at 0, ic at MLP_BYTES

typedef _Float16 f16;
typedef __attribute__((ext_vector_type(8)))  _Float16 f16x8;
typedef __attribute__((ext_vector_type(16))) float    f32x16;

#define C2LOG2E 2.8853900817779268f   // 2*log2(e), folded into W/b of all layers

// tanh(true_x) where x = C2LOG2E*true_x is the folded pre-activation
__device__ __forceinline__ float tanh2(float x){
  float e = __builtin_amdgcn_exp2f(x);
  return 1.0f - 2.0f * __builtin_amdgcn_rcpf(e + 1.0f);
}

__device__ __forceinline__ void gl_lds16(const void* g, void* l){
  __builtin_amdgcn_global_load_lds(
      (const __attribute__((address_space(1))) void*)g,
      (__attribute__((address_space(3))) void*)l, 16, 0, 0);
}

// ---------------- weight packing (r7 layout, verified: C2LOG2E fold on W,b) ----
__global__ void pack_weights(
    const float* __restrict__ dpW0, const float* __restrict__ dpb0,
    const float* __restrict__ dpWh, const float* __restrict__ dpbh,
    const float* __restrict__ dpWo, const float* __restrict__ dpbo,
    const float* __restrict__ icW0, const float* __restrict__ icb0,
    const float* __restrict__ icWh, const float* __restrict__ icbh,
    const float* __restrict__ icWo, const float* __restrict__ icbo,
    unsigned char* __restrict__ ws)
{
  int tid = blockIdx.x * blockDim.x + threadIdx.x;
  int nth = gridDim.x * blockDim.x;
  for (int m = 0; m < 2; ++m){
    const float* W0 = m ? icW0 : dpW0;
    const float* Wh = m ? icWh : dpWh;
    const float* b0 = m ? icb0 : dpb0;
    const float* bh = m ? icbh : dpbh;
    const float* Wo = m ? icWo : dpWo;
    const float* bo = m ? icbo : dpbo;
    const int indim = m ? 5 : 6;
    unsigned char* base = ws + m * MLP_BYTES;

    f16* dstF0 = (f16*)(base + FRAG0_OFF);
    for (int idx = tid; idx < 2048; idx += nth){
      int e    = idx & 7;
      int lane = (idx >> 3) & 63;
      int jt   = idx >> 9;
      int j = 32*jt + (lane & 31);
      int k = 8*(lane >> 5) + e;
      float v = (k < indim) ? W0[k*128 + j] * C2LOG2E : 0.0f;
      dstF0[idx] = (f16)v;
    }
    f16* dstFH = (f16*)(base + FRAGH_OFF);
    for (int idx = tid; idx < 3*16384; idx += nth){
      int layer = idx / 16384;
      int q     = idx & 16383;
      int e    = q & 7;
      int lane = (q >> 3) & 63;
      int f    = q >> 9;            // f = jt*8 + s
      int jt = f >> 3, s = f & 7;
      int j = 32*jt + (lane & 31);
      int k = 16*s + 8*(lane >> 5) + e;
      int row = (k & ~12) | ((k & 4) << 1) | ((k & 8) >> 1); // sigma: swap bits 2,3
      float v = Wh[(layer*128 + row)*128 + j] * C2LOG2E;
      dstFH[idx] = (f16)v;
    }
    float* dstB = (float*)(base + BIAS_OFF);
    for (int idx = tid; idx < 512; idx += nth)
      dstB[idx] = ((idx < 128) ? b0[idx] : bh[idx - 128]) * C2LOG2E;
    float* dstW = (float*)(base + WO_OFF);
    for (int idx = tid; idx < 128; idx += nth) dstW[idx] = Wo[idx];
    if (tid == 0) dstW[128] = bo[0];
  }
}

// ---------------- main fused kernel ----------------
__device__ __forceinline__ f32x16 load_bias16(const float* bp){
  float4 q0 = *(const float4*)(bp +  0);
  float4 q1 = *(const float4*)(bp +  8);
  float4 q2 = *(const float4*)(bp + 16);
  float4 q3 = *(const float4*)(bp + 24);
  f32x16 a;
  a[0]=q0.x;  a[1]=q0.y;  a[2]=q0.z;  a[3]=q0.w;
  a[4]=q1.x;  a[5]=q1.y;  a[6]=q1.z;  a[7]=q1.w;
  a[8]=q2.x;  a[9]=q2.y;  a[10]=q2.z; a[11]=q2.w;
  a[12]=q3.x; a[13]=q3.y; a[14]=q3.z; a[15]=q3.w;
  return a;
}

// 256 blocks x 1024 threads (16 waves = 4/SIMD, LDS-capped at 1 block/CU).
// Each wave owns ONE 32-point column tile, all 128 rows (acc = 4 x f32x16).
// Weights LDS-resident: stage dp once, 3 dp chains, restage ic, ic chain.
// launch_bounds(1024,2): min 2 waves/EU -> 256-reg budget. (1024,4) and the
// default both produced a 64-VGPR allocation + 160MB scratch spill (r8/r9);
// (512,2) produced a clean 128-reg allocation (r6) -> request the loose bound
// and let the ~120-reg working set fit naturally.
__global__ __launch_bounds__(1024, 2) void node_main(
    const float* __restrict__ tx,
    const unsigned char* __restrict__ ws,
    float* __restrict__ out)
{
  __shared__ __align__(16) unsigned char sW[FRAG0_BYTES + FRAGH_BYTES]; // 100KB
  __shared__ __align__(16) float sBias[512];
  __shared__ __align__(16) float sWo[136];

  const int tid  = threadIdx.x;
  const int wave = tid >> 6;
  const int lane = tid & 63;
  const int c    = lane & 31;
  const int hi   = lane >> 5;
  const int gp   = blockIdx.x * 512 + wave * 32 + c;

  auto stage = [&](const unsigned char* mb){
    for (int k = wave; k < WCHUNKS; k += 16)
      gl_lds16(mb + k*1024 + lane*16, sW + k*1024);
    for (int i = tid; i < 128; i += 1024)
      ((uint4*)sBias)[i] = ((const uint4*)(mb + BIAS_OFF))[i];
    for (int i = tid; i < 33; i += 1024)
      ((uint4*)sWo)[i] = ((const uint4*)(mb + WO_OFF))[i];
  };

  stage(ws);                       // dp weights -> LDS (issue before feature math)

  // ---- features (hi halves redundant: broadcast loads) ----
  float4 cc = ((const float4*)tx)[gp];
  float x = cc.y, y = cc.z, z = cc.w;
  float xy = x*x + y*y;
  float r    = sqrtf(xy + z*z + 1e-8f);
  float rho  = sqrtf(xy + 1e-8f);
  float rin  = __builtin_amdgcn_rcpf(r);
  float rhin = __builtin_amdgcn_rcpf(rho);
  float u    = r * __builtin_amdgcn_rcpf(1.0f + r);
  float cth  = z * rin;
  float sth  = rho * rin;
  float cph  = x * rhin;
  float sph  = y * rhin;
  float th   = 0.5f * cc.x;     // a = t/2 (t0 = 0)

  float vsum = 0.0f;

  auto run_chain = [&](int chain){
    const float gn = (chain == 0) ? -0.7745966692414834f :
                     (chain == 2) ?  0.7745966692414834f : 0.0f;
    // input B-frag: k-slot = feature index (hi half = zero padding)
    f16x8 b0f;
    #pragma unroll
    for (int e = 0; e < 8; ++e) b0f[e] = (f16)0.0f;
    if (hi == 0){
      if (chain == 3){
        b0f[0]=(f16)u;   b0f[1]=(f16)cth; b0f[2]=(f16)sth;
        b0f[3]=(f16)cph; b0f[4]=(f16)sph;
      } else {
        float ts = th * (1.0f + gn);
        b0f[0]=(f16)ts;  b0f[1]=(f16)u;   b0f[2]=(f16)cth;
        b0f[3]=(f16)sth; b0f[4]=(f16)cph; b0f[5]=(f16)sph;
      }
    }

    f32x16 acc[4];
    // ---- input layer (bias as MFMA C-in) ----
    {
      const f16x8* fr = (const f16x8*)sW;
      #pragma unroll
      for (int jt = 0; jt < 4; ++jt)
        acc[jt] = __builtin_amdgcn_mfma_f32_32x32x16_f16(
                    fr[jt*64 + lane], b0f,
                    load_bias16(&sBias[32*jt + 4*hi]), 0,0,0);
    }

    // ---- 3 hidden layers, weights resident in LDS, B in registers ----
    #pragma unroll 1
    for (int L = 0; L < 3; ++L){
      union { f16x8 v; unsigned uu[4]; } bf[8];
      #pragma unroll
      for (int jt = 0; jt < 4; ++jt)
        #pragma unroll
        for (int cq = 0; cq < 2; ++cq)
          #pragma unroll
          for (int e = 0; e < 4; ++e){
            float t0 = tanh2(acc[jt][8*cq + 2*e]);
            float t1 = tanh2(acc[jt][8*cq + 2*e + 1]);
            auto pk = __builtin_amdgcn_cvt_pkrtz(t0, t1);
            bf[2*jt + cq].uu[e] = __builtin_bit_cast(unsigned, pk);
          }
      const f16x8* fh = (const f16x8*)(sW + FRAGH_OFF + L*HLAYER_BYTES);
      #pragma unroll
      for (int jt = 0; jt < 4; ++jt){
        f32x16 t = load_bias16(&sBias[(L+1)*128 + 32*jt + 4*hi]);
        #pragma unroll
        for (int s = 0; s < 8; ++s)
          t = __builtin_amdgcn_mfma_f32_32x32x16_f16(
                fh[(jt*8 + s)*64 + lane], bf[s].v, t, 0,0,0);
        acc[jt] = t;
      }
    }

    // ---- output layer: v = sum_j tanh(h_j) * Wo[j] + bo ----
    float v = 0.0f;
    #pragma unroll
    for (int jt = 0; jt < 4; ++jt){
      const float* wp = &sWo[32*jt + 4*hi];
      float4 q0 = *(const float4*)(wp +  0);
      float4 q1 = *(const float4*)(wp +  8);
      float4 q2 = *(const float4*)(wp + 16);
      float4 q3 = *(const float4*)(wp + 24);
      f32x16 A = acc[jt];
      v += tanh2(A[0])*q0.x  + tanh2(A[1])*q0.y
         + tanh2(A[2])*q0.z  + tanh2(A[3])*q0.w
         + tanh2(A[4])*q1.x  + tanh2(A[5])*q1.y
         + tanh2(A[6])*q1.z  + tanh2(A[7])*q1.w
         + tanh2(A[8])*q2.x  + tanh2(A[9])*q2.y
         + tanh2(A[10])*q2.z + tanh2(A[11])*q2.w
         + tanh2(A[12])*q3.x + tanh2(A[13])*q3.y
         + tanh2(A[14])*q3.z + tanh2(A[15])*q3.w;
    }
    v += __shfl_xor(v, 32);            // combine the two row-halves
    v += sWo[128];                     // bo
    if (chain == 3) vsum += v;
    else {
      const float wq = (chain == 1) ? 0.8888888888888889f
                                    : 0.5555555555555556f;
      vsum = __builtin_fmaf(th * wq, v, vsum);
    }
  };

  __syncthreads();                 // dp staging visible
  #pragma unroll 1
  for (int chain = 0; chain < 3; ++chain) run_chain(chain);
  __syncthreads();                 // all waves done reading dp weights
  stage(ws + MLP_BYTES);           // ic weights over same LDS
  __syncthreads();
  run_chain(3);

  if (hi == 0) out[gp] = vsum;
}

extern "C" void kernel_launch(void* const* d_in, const int* in_sizes, int n_in,
                              void* d_out, int out_size, void* d_ws, size_t ws_size,
                              hipStream_t stream)
{
  const float* tx = (const float*)d_in[0];
  pack_weights<<<64, 256, 0, stream>>>(
      (const float*)d_in[1],  (const float*)d_in[2],  (const float*)d_in[3],
      (const float*)d_in[4],  (const float*)d_in[5],  (const float*)d_in[6],
      (const float*)d_in[7],  (const float*)d_in[8],  (const float*)d_in[9],
      (const float*)d_in[10], (const float*)d_in[11], (const float*)d_in[12],
      (unsigned char*)d_ws);
  node_main<<<NPTS/512, 1024, 0, stream>>>(tx, (const unsigned char*)d_ws, (float*)d_out);
}

// Round 11
// 92.723 us; speedup vs baseline: 1.3971x; 1.3970x over previous
//
#include <hip/hip_runtime.h>

#define NPTS 131072

#define FRAG0_OFF    0
#define FRAG0_BYTES  4096
#define FRAGH_OFF    4096
#define HLAYER_BYTES 32768
#define FRAGH_BYTES  (3 * HLAYER_BYTES)
#define BIAS_OFF     (FRAGH_OFF + FRAGH_BYTES)   // 102400
#define BIAS_BYTES   2048
#define WO_OFF       (BIAS_OFF + BIAS_BYTES)     // 104448
#define WOBO_BYTES   528
#define MLP_BYTES    (WO_OFF + WOBO_BYTES)       // dp at 0, ic at MLP_BYTES

typedef _Float16 f16;
typedef __attribute__((ext_vector_type(8)))  _Float16 f16x8;
typedef __attribute__((ext_vector_type(16))) float    f32x16;

#define C2LOG2E 2.8853900817779268f   // 2*log2(e), folded into W/b of all layers

// tanh(true_x) where x = C2LOG2E*true_x is the folded pre-activation
__device__ __forceinline__ float tanh2(float x){
  float e = __builtin_amdgcn_exp2f(x);
  return 1.0f - 2.0f * __builtin_amdgcn_rcpf(e + 1.0f);
}

__device__ __forceinline__ void gl_lds16(const void* g, void* l){
  __builtin_amdgcn_global_load_lds(
      (const __attribute__((address_space(1))) void*)g,
      (__attribute__((address_space(3))) void*)l, 16, 0, 0);
}

// ---------------- weight packing (r7 layout, verified: C2LOG2E fold on W,b) ----
__global__ void pack_weights(
    const float* __restrict__ dpW0, const float* __restrict__ dpb0,
    const float* __restrict__ dpWh, const float* __restrict__ dpbh,
    const float* __restrict__ dpWo, const float* __restrict__ dpbo,
    const float* __restrict__ icW0, const float* __restrict__ icb0,
    const float* __restrict__ icWh, const float* __restrict__ icbh,
    const float* __restrict__ icWo, const float* __restrict__ icbo,
    unsigned char* __restrict__ ws)
{
  int tid = blockIdx.x * blockDim.x + threadIdx.x;
  int nth = gridDim.x * blockDim.x;
  for (int m = 0; m < 2; ++m){
    const float* W0 = m ? icW0 : dpW0;
    const float* Wh = m ? icWh : dpWh;
    const float* b0 = m ? icb0 : dpb0;
    const float* bh = m ? icbh : dpbh;
    const float* Wo = m ? icWo : dpWo;
    const float* bo = m ? icbo : dpbo;
    const int indim = m ? 5 : 6;
    unsigned char* base = ws + m * MLP_BYTES;

    f16* dstF0 = (f16*)(base + FRAG0_OFF);
    for (int idx = tid; idx < 2048; idx += nth){
      int e    = idx & 7;
      int lane = (idx >> 3) & 63;
      int jt   = idx >> 9;
      int j = 32*jt + (lane & 31);
      int k = 8*(lane >> 5) + e;
      float v = (k < indim) ? W0[k*128 + j] * C2LOG2E : 0.0f;
      dstF0[idx] = (f16)v;
    }
    f16* dstFH = (f16*)(base + FRAGH_OFF);
    for (int idx = tid; idx < 3*16384; idx += nth){
      int layer = idx / 16384;
      int q     = idx & 16383;
      int e    = q & 7;
      int lane = (q >> 3) & 63;
      int f    = q >> 9;            // f = jt*8 + s
      int jt = f >> 3, s = f & 7;
      int j = 32*jt + (lane & 31);
      int k = 16*s + 8*(lane >> 5) + e;
      int row = (k & ~12) | ((k & 4) << 1) | ((k & 8) >> 1); // sigma: swap bits 2,3
      float v = Wh[(layer*128 + row)*128 + j] * C2LOG2E;
      dstFH[idx] = (f16)v;
    }
    float* dstB = (float*)(base + BIAS_OFF);
    for (int idx = tid; idx < 512; idx += nth)
      dstB[idx] = ((idx < 128) ? b0[idx] : bh[idx - 128]) * C2LOG2E;
    float* dstW = (float*)(base + WO_OFF);
    for (int idx = tid; idx < 128; idx += nth) dstW[idx] = Wo[idx];
    if (tid == 0) dstW[128] = bo[0];
  }
}

// ---------------- main fused kernel ----------------
__device__ __forceinline__ f32x16 load_bias16(const float* bp){
  float4 q0 = *(const float4*)(bp +  0);
  float4 q1 = *(const float4*)(bp +  8);
  float4 q2 = *(const float4*)(bp + 16);
  float4 q3 = *(const float4*)(bp + 24);
  f32x16 a;
  a[0]=q0.x;  a[1]=q0.y;  a[2]=q0.z;  a[3]=q0.w;
  a[4]=q1.x;  a[5]=q1.y;  a[6]=q1.z;  a[7]=q1.w;
  a[8]=q2.x;  a[9]=q2.y;  a[10]=q2.z; a[11]=q2.w;
  a[12]=q3.x; a[13]=q3.y; a[14]=q3.z; a[15]=q3.w;
  return a;
}

// 1024 blocks x 256 threads (4 waves). Each wave owns one 32-point column tile,
// all 128 rows (acc = 4 x f32x16). LDS = 38.5KB: F0 + bias/Wo resident per MLP
// phase; hidden layers STREAM through two 16KB half-layer buffers (double-
// buffered global_load_lds; buffer parity == half, so all indices are static).
// 38.5KB x 4 blocks = 154KB -> up to 4 blocks/CU = 16 waves/CU (vs r6's 8).
// launch_bounds(256,2): empirical allocator law budget = 256/max(2, 4/4) = 128.
__global__ __launch_bounds__(256, 2) void node_main(
    const float* __restrict__ tx,
    const unsigned char* __restrict__ ws,
    float* __restrict__ out)
{
  __shared__ __align__(16) unsigned char sHL[2 * 16384]; // half-layer dbuf
  __shared__ __align__(16) unsigned char sF0[FRAG0_BYTES];
  __shared__ __align__(16) float sBias[512];
  __shared__ __align__(16) float sWo[136];

  const int tid  = threadIdx.x;
  const int wave = tid >> 6;
  const int lane = tid & 63;
  const int c    = lane & 31;
  const int hi   = lane >> 5;
  const int gp   = blockIdx.x * 128 + wave * 32 + c;

  // stage one half-layer (16KB = 16 chunks of 1KB) into buffer b
  auto stage_half = [&](const unsigned char* mb, int L, int half, int b){
    const unsigned char* src = mb + FRAGH_OFF + L*HLAYER_BYTES + half*4096;
    unsigned char* dst = sHL + b*16384;
    #pragma unroll
    for (int k = 0; k < 4; ++k){          // chunk idx = wave + 4k
      int ch = wave + 4*k;
      gl_lds16(src + (ch>>2)*8192 + (ch&3)*1024 + lane*16, dst + ch*1024);
    }
  };
  // per-MLP entry staging: F0 + bias + Wo + first half-layer (L0 half0 -> buf0)
  auto stage_entry = [&](const unsigned char* mb){
    gl_lds16(mb + FRAG0_OFF + wave*1024 + lane*16, sF0 + wave*1024);
    for (int i = tid; i < 128; i += 256)
      ((uint4*)sBias)[i] = ((const uint4*)(mb + BIAS_OFF))[i];
    for (int i = tid; i < 33; i += 256)
      ((uint4*)sWo)[i] = ((const uint4*)(mb + WO_OFF))[i];
    stage_half(mb, 0, 0, 0);
  };

  stage_entry(ws);                 // dp entry staging (async, visible at 1st barrier)

  // ---- features ----
  float4 cc = ((const float4*)tx)[gp];
  float x = cc.y, y = cc.z, z = cc.w;
  float xy = x*x + y*y;
  float r    = sqrtf(xy + z*z + 1e-8f);
  float rho  = sqrtf(xy + 1e-8f);
  float rin  = __builtin_amdgcn_rcpf(r);
  float rhin = __builtin_amdgcn_rcpf(rho);
  float u    = r * __builtin_amdgcn_rcpf(1.0f + r);
  float cth  = z * rin;
  float sth  = rho * rin;
  float cph  = x * rhin;
  float sph  = y * rhin;
  float th   = 0.5f * cc.x;        // a = t/2 (t0 = 0)

  float vsum = 0.0f;

  auto run_phase = [&](const unsigned char* mb, int c0, int c1){
    f32x16 acc[4];
    union { f16x8 v; unsigned uu[4]; } bf[8];

    #pragma unroll 1
    for (int chain = c0; chain <= c1; ++chain){
      #pragma unroll 1
      for (int L = 0; L < 3; ++L){
        #pragma unroll
        for (int half = 0; half < 2; ++half){
          __syncthreads();               // staged buf[half] visible; prev readers done
          // stage the NEXT half into buf[1-half]
          if (half == 0)           stage_half(mb, L,   1, 1);
          else if (L < 2)          stage_half(mb, L+1, 0, 0);
          else if (chain < c1)     stage_half(mb, 0,   0, 0);

          if (L == 0 && half == 0){
            // ---- chain start: input B-frag + input layer + pack ----
            f16x8 b0f;
            #pragma unroll
            for (int e = 0; e < 8; ++e) b0f[e] = (f16)0.0f;
            if (hi == 0){
              if (chain == 3){
                b0f[0]=(f16)u;   b0f[1]=(f16)cth; b0f[2]=(f16)sth;
                b0f[3]=(f16)cph; b0f[4]=(f16)sph;
              } else {
                const float gn = (chain == 0) ? -0.7745966692414834f :
                                 (chain == 2) ?  0.7745966692414834f : 0.0f;
                float ts = th * (1.0f + gn);
                b0f[0]=(f16)ts;  b0f[1]=(f16)u;   b0f[2]=(f16)cth;
                b0f[3]=(f16)sth; b0f[4]=(f16)cph; b0f[5]=(f16)sph;
              }
            }
            const f16x8* fr = (const f16x8*)sF0;
            #pragma unroll
            for (int jt = 0; jt < 4; ++jt)
              acc[jt] = __builtin_amdgcn_mfma_f32_32x32x16_f16(
                          fr[jt*64 + lane], b0f,
                          load_bias16(&sBias[32*jt + 4*hi]), 0,0,0);
            #pragma unroll
            for (int jt = 0; jt < 4; ++jt)
              #pragma unroll
              for (int cq = 0; cq < 2; ++cq)
                #pragma unroll
                for (int e = 0; e < 4; ++e){
                  float t0 = tanh2(acc[jt][8*cq + 2*e]);
                  float t1 = tanh2(acc[jt][8*cq + 2*e + 1]);
                  auto pk = __builtin_amdgcn_cvt_pkrtz(t0, t1);
                  bf[2*jt + cq].uu[e] = __builtin_bit_cast(unsigned, pk);
                }
          }

          // ---- consume half: 16 MFMA from buf[half] ----
          const f16x8* fb = (const f16x8*)(sHL + half*16384);
          #pragma unroll
          for (int jt = 0; jt < 4; ++jt){
            f32x16 t = (half == 0)
                     ? load_bias16(&sBias[(L+1)*128 + 32*jt + 4*hi])
                     : acc[jt];
            #pragma unroll
            for (int s2 = 0; s2 < 4; ++s2)
              t = __builtin_amdgcn_mfma_f32_32x32x16_f16(
                    fb[(jt*4 + s2)*64 + lane], bf[4*half + s2].v, t, 0,0,0);
            acc[jt] = t;
          }

          if (half == 1){
            if (L < 2){
              // ---- pack for next layer ----
              #pragma unroll
              for (int jt = 0; jt < 4; ++jt)
                #pragma unroll
                for (int cq = 0; cq < 2; ++cq)
                  #pragma unroll
                  for (int e = 0; e < 4; ++e){
                    float t0 = tanh2(acc[jt][8*cq + 2*e]);
                    float t1 = tanh2(acc[jt][8*cq + 2*e + 1]);
                    auto pk = __builtin_amdgcn_cvt_pkrtz(t0, t1);
                    bf[2*jt + cq].uu[e] = __builtin_bit_cast(unsigned, pk);
                  }
            } else {
              // ---- output dot ----
              float v = 0.0f;
              #pragma unroll
              for (int jt = 0; jt < 4; ++jt){
                const float* wp = &sWo[32*jt + 4*hi];
                float4 q0 = *(const float4*)(wp +  0);
                float4 q1 = *(const float4*)(wp +  8);
                float4 q2 = *(const float4*)(wp + 16);
                float4 q3 = *(const float4*)(wp + 24);
                f32x16 A = acc[jt];
                v += tanh2(A[0])*q0.x  + tanh2(A[1])*q0.y
                   + tanh2(A[2])*q0.z  + tanh2(A[3])*q0.w
                   + tanh2(A[4])*q1.x  + tanh2(A[5])*q1.y
                   + tanh2(A[6])*q1.z  + tanh2(A[7])*q1.w
                   + tanh2(A[8])*q2.x  + tanh2(A[9])*q2.y
                   + tanh2(A[10])*q2.z + tanh2(A[11])*q2.w
                   + tanh2(A[12])*q3.x + tanh2(A[13])*q3.y
                   + tanh2(A[14])*q3.z + tanh2(A[15])*q3.w;
              }
              v += __shfl_xor(v, 32);    // combine the two row-halves
              v += sWo[128];             // bo
              if (chain == 3) vsum += v;
              else {
                const float wq = (chain == 1) ? 0.8888888888888889f
                                              : 0.5555555555555556f;
                vsum = __builtin_fmaf(th * wq, v, vsum);
              }
            }
          }
        }
      }
    }
  };

  run_phase(ws, 0, 2);             // 3 dp chains (weights restream, L2-hot)
  __syncthreads();                 // dp smalls (sWo/sBias/sF0) no longer needed
  stage_entry(ws + MLP_BYTES);     // ic entry staging
  run_phase(ws + MLP_BYTES, 3, 3); // ic chain

  if (hi == 0) out[gp] = vsum;
}

extern "C" void kernel_launch(void* const* d_in, const int* in_sizes, int n_in,
                              void* d_out, int out_size, void* d_ws, size_t ws_size,
                              hipStream_t stream)
{
  const float* tx = (const float*)d_in[0];
  pack_weights<<<64, 256, 0, stream>>>(
      (const float*)d_in[1],  (const float*)d_in[2],  (const float*)d_in[3],
      (const float*)d_in[4],  (const float*)d_in[5],  (const float*)d_in[6],
      (const float*)d_in[7],  (const float*)d_in[8],  (const float*)d_in[9],
      (const float*)d_in[10], (const float*)d_in[11], (const float*)d_in[12],
      (unsigned char*)d_ws);
  node_main<<<NPTS/128, 256, 0, stream>>>(tx, (const unsigned char*)d_ws, (float*)d_out);
}

// Round 12
// 92.442 us; speedup vs baseline: 1.4014x; 1.0030x over previous
//
#include <hip/hip_runtime.h>

#define NPTS 131072

#define FRAG0_OFF    0
#define FRAG0_BYTES  4096
#define FRAGH_OFF    4096
#define HLAYER_BYTES 32768
#define FRAGH_BYTES  (3 * HLAYER_BYTES)
#define BIAS_OFF     (FRAGH_OFF + FRAGH_BYTES)   // 102400
#define BIAS_BYTES   2048
#define WO_OFF       (BIAS_OFF + BIAS_BYTES)     // 104448
#define WOBO_BYTES   528
#define MLP_BYTES    (WO_OFF + WOBO_BYTES)       // dp at 0, ic at MLP_BYTES

typedef _Float16 f16;
typedef __attribute__((ext_vector_type(8)))  _Float16 f16x8;
typedef __attribute__((ext_vector_type(16))) float    f32x16;

#define C2LOG2E 2.8853900817779268f   // 2*log2(e), folded into W/b of all layers

// tanh(true_x) where x = C2LOG2E*true_x is the folded pre-activation
__device__ __forceinline__ float tanh2(float x){
  float e = __builtin_amdgcn_exp2f(x);
  return 1.0f - 2.0f * __builtin_amdgcn_rcpf(e + 1.0f);
}

__device__ __forceinline__ void gl_lds16(const void* g, void* l){
  __builtin_amdgcn_global_load_lds(
      (const __attribute__((address_space(1))) void*)g,
      (__attribute__((address_space(3))) void*)l, 16, 0, 0);
}

// ---------------- weight packing (r7 layout, verified: C2LOG2E fold on W,b) ----
__global__ void pack_weights(
    const float* __restrict__ dpW0, const float* __restrict__ dpb0,
    const float* __restrict__ dpWh, const float* __restrict__ dpbh,
    const float* __restrict__ dpWo, const float* __restrict__ dpbo,
    const float* __restrict__ icW0, const float* __restrict__ icb0,
    const float* __restrict__ icWh, const float* __restrict__ icbh,
    const float* __restrict__ icWo, const float* __restrict__ icbo,
    unsigned char* __restrict__ ws)
{
  int tid = blockIdx.x * blockDim.x + threadIdx.x;
  int nth = gridDim.x * blockDim.x;
  for (int m = 0; m < 2; ++m){
    const float* W0 = m ? icW0 : dpW0;
    const float* Wh = m ? icWh : dpWh;
    const float* b0 = m ? icb0 : dpb0;
    const float* bh = m ? icbh : dpbh;
    const float* Wo = m ? icWo : dpWo;
    const float* bo = m ? icbo : dpbo;
    const int indim = m ? 5 : 6;
    unsigned char* base = ws + m * MLP_BYTES;

    f16* dstF0 = (f16*)(base + FRAG0_OFF);
    for (int idx = tid; idx < 2048; idx += nth){
      int e    = idx & 7;
      int lane = (idx >> 3) & 63;
      int jt   = idx >> 9;
      int j = 32*jt + (lane & 31);
      int k = 8*(lane >> 5) + e;
      float v = (k < indim) ? W0[k*128 + j] * C2LOG2E : 0.0f;
      dstF0[idx] = (f16)v;
    }
    f16* dstFH = (f16*)(base + FRAGH_OFF);
    for (int idx = tid; idx < 3*16384; idx += nth){
      int layer = idx / 16384;
      int q     = idx & 16383;
      int e    = q & 7;
      int lane = (q >> 3) & 63;
      int f    = q >> 9;            // f = jt*8 + s
      int jt = f >> 3, s = f & 7;
      int j = 32*jt + (lane & 31);
      int k = 16*s + 8*(lane >> 5) + e;
      int row = (k & ~12) | ((k & 4) << 1) | ((k & 8) >> 1); // sigma: swap bits 2,3
      float v = Wh[(layer*128 + row)*128 + j] * C2LOG2E;
      dstFH[idx] = (f16)v;
    }
    float* dstB = (float*)(base + BIAS_OFF);
    for (int idx = tid; idx < 512; idx += nth)
      dstB[idx] = ((idx < 128) ? b0[idx] : bh[idx - 128]) * C2LOG2E;
    float* dstW = (float*)(base + WO_OFF);
    for (int idx = tid; idx < 128; idx += nth) dstW[idx] = Wo[idx];
    if (tid == 0) dstW[128] = bo[0];
  }
}

// ---------------- main fused kernel ----------------
__device__ __forceinline__ f32x16 load_bias16(const float* bp){
  float4 q0 = *(const float4*)(bp +  0);
  float4 q1 = *(const float4*)(bp +  8);
  float4 q2 = *(const float4*)(bp + 16);
  float4 q3 = *(const float4*)(bp + 24);
  f32x16 a;
  a[0]=q0.x;  a[1]=q0.y;  a[2]=q0.z;  a[3]=q0.w;
  a[4]=q1.x;  a[5]=q1.y;  a[6]=q1.z;  a[7]=q1.w;
  a[8]=q2.x;  a[9]=q2.y;  a[10]=q2.z; a[11]=q2.w;
  a[12]=q3.x; a[13]=q3.y; a[14]=q3.z; a[15]=q3.w;
  return a;
}

// Pin a value into arch VGPRs (not AGPRs): empty asm with "+v" forces the
// register class; coalescing makes the MFMA D-operand allocate there, killing
// the v_accvgpr_read/write tax and keeping the unified reg total <=128
// (=> 4 waves/SIMD tier). gfx950 unified RF makes this legal either way.
#define PIN_V(x) asm("" : "+v"(x))

// 1024 blocks x 256 threads (4 waves). Each wave owns one 32-point column tile,
// all 128 rows (acc = 4 x f32x16, PINNED to arch VGPRs). LDS = 39KB: F0 +
// bias/Wo resident per MLP phase; hidden layers stream through two 16KB
// half-layer dbuf buffers (global_load_lds). Target: total regs <=128 ->
// 4 waves/SIMD, 4 blocks/CU (159.7KB LDS).
__global__ __launch_bounds__(256, 2) void node_main(
    const float* __restrict__ tx,
    const unsigned char* __restrict__ ws,
    float* __restrict__ out)
{
  __shared__ __align__(16) unsigned char sHL[2 * 16384]; // half-layer dbuf
  __shared__ __align__(16) unsigned char sF0[FRAG0_BYTES];
  __shared__ __align__(16) float sBias[512];
  __shared__ __align__(16) float sWo[136];

  const int tid  = threadIdx.x;
  const int wave = tid >> 6;
  const int lane = tid & 63;
  const int c    = lane & 31;
  const int hi   = lane >> 5;
  const int gp   = blockIdx.x * 128 + wave * 32 + c;

  // stage one half-layer (16KB = 16 chunks of 1KB) into buffer b
  auto stage_half = [&](const unsigned char* mb, int L, int half, int b){
    const unsigned char* src = mb + FRAGH_OFF + L*HLAYER_BYTES + half*4096;
    unsigned char* dst = sHL + b*16384;
    #pragma unroll
    for (int k = 0; k < 4; ++k){          // chunk idx = wave + 4k
      int ch = wave + 4*k;
      gl_lds16(src + (ch>>2)*8192 + (ch&3)*1024 + lane*16, dst + ch*1024);
    }
  };
  // per-MLP entry staging: F0 + bias + Wo + first half-layer (L0 half0 -> buf0)
  auto stage_entry = [&](const unsigned char* mb){
    gl_lds16(mb + FRAG0_OFF + wave*1024 + lane*16, sF0 + wave*1024);
    for (int i = tid; i < 128; i += 256)
      ((uint4*)sBias)[i] = ((const uint4*)(mb + BIAS_OFF))[i];
    for (int i = tid; i < 33; i += 256)
      ((uint4*)sWo)[i] = ((const uint4*)(mb + WO_OFF))[i];
    stage_half(mb, 0, 0, 0);
  };

  stage_entry(ws);                 // dp entry staging (async, visible at 1st barrier)

  // ---- features ----
  float4 cc = ((const float4*)tx)[gp];
  float x = cc.y, y = cc.z, z = cc.w;
  float xy = x*x + y*y;
  float r    = sqrtf(xy + z*z + 1e-8f);
  float rho  = sqrtf(xy + 1e-8f);
  float rin  = __builtin_amdgcn_rcpf(r);
  float rhin = __builtin_amdgcn_rcpf(rho);
  float u    = r * __builtin_amdgcn_rcpf(1.0f + r);
  float cth  = z * rin;
  float sth  = rho * rin;
  float cph  = x * rhin;
  float sph  = y * rhin;
  float th   = 0.5f * cc.x;        // a = t/2 (t0 = 0)

  float vsum = 0.0f;

  auto run_phase = [&](const unsigned char* mb, int c0, int c1){
    f32x16 acc[4];
    union { f16x8 v; unsigned uu[4]; } bf[8];

    #pragma unroll 1
    for (int chain = c0; chain <= c1; ++chain){
      #pragma unroll 1
      for (int L = 0; L < 3; ++L){
        #pragma unroll
        for (int half = 0; half < 2; ++half){
          __syncthreads();               // staged buf[half] visible; prev readers done
          // stage the NEXT half into buf[1-half]
          if (half == 0)           stage_half(mb, L,   1, 1);
          else if (L < 2)          stage_half(mb, L+1, 0, 0);
          else if (chain < c1)     stage_half(mb, 0,   0, 0);

          if (L == 0 && half == 0){
            // ---- chain start: input B-frag + input layer + pack ----
            f16x8 b0f;
            #pragma unroll
            for (int e = 0; e < 8; ++e) b0f[e] = (f16)0.0f;
            if (hi == 0){
              if (chain == 3){
                b0f[0]=(f16)u;   b0f[1]=(f16)cth; b0f[2]=(f16)sth;
                b0f[3]=(f16)cph; b0f[4]=(f16)sph;
              } else {
                const float gn = (chain == 0) ? -0.7745966692414834f :
                                 (chain == 2) ?  0.7745966692414834f : 0.0f;
                float ts = th * (1.0f + gn);
                b0f[0]=(f16)ts;  b0f[1]=(f16)u;   b0f[2]=(f16)cth;
                b0f[3]=(f16)sth; b0f[4]=(f16)cph; b0f[5]=(f16)sph;
              }
            }
            const f16x8* fr = (const f16x8*)sF0;
            #pragma unroll
            for (int jt = 0; jt < 4; ++jt){
              acc[jt] = __builtin_amdgcn_mfma_f32_32x32x16_f16(
                          fr[jt*64 + lane], b0f,
                          load_bias16(&sBias[32*jt + 4*hi]), 0,0,0);
              PIN_V(acc[jt]);
            }
            #pragma unroll
            for (int jt = 0; jt < 4; ++jt)
              #pragma unroll
              for (int cq = 0; cq < 2; ++cq)
                #pragma unroll
                for (int e = 0; e < 4; ++e){
                  float t0 = tanh2(acc[jt][8*cq + 2*e]);
                  float t1 = tanh2(acc[jt][8*cq + 2*e + 1]);
                  auto pk = __builtin_amdgcn_cvt_pkrtz(t0, t1);
                  bf[2*jt + cq].uu[e] = __builtin_bit_cast(unsigned, pk);
                }
          }

          // ---- consume half: 16 MFMA from buf[half] ----
          const f16x8* fb = (const f16x8*)(sHL + half*16384);
          #pragma unroll
          for (int jt = 0; jt < 4; ++jt){
            f32x16 t = (half == 0)
                     ? load_bias16(&sBias[(L+1)*128 + 32*jt + 4*hi])
                     : acc[jt];
            #pragma unroll
            for (int s2 = 0; s2 < 4; ++s2)
              t = __builtin_amdgcn_mfma_f32_32x32x16_f16(
                    fb[(jt*4 + s2)*64 + lane], bf[4*half + s2].v, t, 0,0,0);
            PIN_V(t);
            acc[jt] = t;
          }

          if (half == 1){
            if (L < 2){
              // ---- pack for next layer ----
              #pragma unroll
              for (int jt = 0; jt < 4; ++jt)
                #pragma unroll
                for (int cq = 0; cq < 2; ++cq)
                  #pragma unroll
                  for (int e = 0; e < 4; ++e){
                    float t0 = tanh2(acc[jt][8*cq + 2*e]);
                    float t1 = tanh2(acc[jt][8*cq + 2*e + 1]);
                    auto pk = __builtin_amdgcn_cvt_pkrtz(t0, t1);
                    bf[2*jt + cq].uu[e] = __builtin_bit_cast(unsigned, pk);
                  }
            } else {
              // ---- output dot ----
              float v = 0.0f;
              #pragma unroll
              for (int jt = 0; jt < 4; ++jt){
                const float* wp = &sWo[32*jt + 4*hi];
                float4 q0 = *(const float4*)(wp +  0);
                float4 q1 = *(const float4*)(wp +  8);
                float4 q2 = *(const float4*)(wp + 16);
                float4 q3 = *(const float4*)(wp + 24);
                f32x16 A = acc[jt];
                v += tanh2(A[0])*q0.x  + tanh2(A[1])*q0.y
                   + tanh2(A[2])*q0.z  + tanh2(A[3])*q0.w
                   + tanh2(A[4])*q1.x  + tanh2(A[5])*q1.y
                   + tanh2(A[6])*q1.z  + tanh2(A[7])*q1.w
                   + tanh2(A[8])*q2.x  + tanh2(A[9])*q2.y
                   + tanh2(A[10])*q2.z + tanh2(A[11])*q2.w
                   + tanh2(A[12])*q3.x + tanh2(A[13])*q3.y
                   + tanh2(A[14])*q3.z + tanh2(A[15])*q3.w;
              }
              v += __shfl_xor(v, 32);    // combine the two row-halves
              v += sWo[128];             // bo
              if (chain == 3) vsum += v;
              else {
                const float wq = (chain == 1) ? 0.8888888888888889f
                                              : 0.5555555555555556f;
                vsum = __builtin_fmaf(th * wq, v, vsum);
              }
            }
          }
        }
      }
    }
  };

  run_phase(ws, 0, 2);             // 3 dp chains (weights restream, L2-hot)
  __syncthreads();                 // dp smalls (sWo/sBias/sF0) no longer needed
  stage_entry(ws + MLP_BYTES);     // ic entry staging
  run_phase(ws + MLP_BYTES, 3, 3); // ic chain

  if (hi == 0) out[gp] = vsum;
}

extern "C" void kernel_launch(void* const* d_in, const int* in_sizes, int n_in,
                              void* d_out, int out_size, void* d_ws, size_t ws_size,
                              hipStream_t stream)
{
  const float* tx = (const float*)d_in[0];
  pack_weights<<<64, 256, 0, stream>>>(
      (const float*)d_in[1],  (const float*)d_in[2],  (const float*)d_in[3],
      (const float*)d_in[4],  (const float*)d_in[5],  (const float*)d_in[6],
      (const float*)d_in[7],  (const float*)d_in[8],  (const float*)d_in[9],
      (const float*)d_in[10], (const float*)d_in[11], (const float*)d_in[12],
      (unsigned char*)d_ws);
  node_main<<<NPTS/128, 256, 0, stream>>>(tx, (const unsigned char*)d_ws, (float*)d_out);
}

// Round 13
// 88.579 us; speedup vs baseline: 1.4625x; 1.0436x over previous
//
#include <hip/hip_runtime.h>

#define NPTS 131072

#define FRAG0_OFF    0
#define FRAG0_BYTES  4096
#define FRAGH_OFF    4096
#define HLAYER_BYTES 32768
#define FRAGH_BYTES  (3 * HLAYER_BYTES)
#define BIAS_OFF     (FRAGH_OFF + FRAGH_BYTES)   // 102400
#define BIAS_BYTES   2048
#define WO_OFF       (BIAS_OFF + BIAS_BYTES)     // 104448
#define WOBO_BYTES   528
#define MLP_BYTES    (WO_OFF + WOBO_BYTES)       // dp at 0, ic at MLP_BYTES

typedef _Float16 f16;
typedef __attribute__((ext_vector_type(8)))  _Float16 f16x8;
typedef __attribute__((ext_vector_type(16))) float    f32x16;

#define C2LOG2E 2.8853900817779268f   // 2*log2(e), folded into W/b of all layers

// tanh(true_x) where x = C2LOG2E*true_x is the folded pre-activation
__device__ __forceinline__ float tanh2(float x){
  float e = __builtin_amdgcn_exp2f(x);
  return 1.0f - 2.0f * __builtin_amdgcn_rcpf(e + 1.0f);
}

__device__ __forceinline__ void gl_lds16(const void* g, void* l){
  __builtin_amdgcn_global_load_lds(
      (const __attribute__((address_space(1))) void*)g,
      (__attribute__((address_space(3))) void*)l, 16, 0, 0);
}

// ---------------- weight packing (r7 layout, verified: C2LOG2E fold on W,b) ----
__global__ void pack_weights(
    const float* __restrict__ dpW0, const float* __restrict__ dpb0,
    const float* __restrict__ dpWh, const float* __restrict__ dpbh,
    const float* __restrict__ dpWo, const float* __restrict__ dpbo,
    const float* __restrict__ icW0, const float* __restrict__ icb0,
    const float* __restrict__ icWh, const float* __restrict__ icbh,
    const float* __restrict__ icWo, const float* __restrict__ icbo,
    unsigned char* __restrict__ ws)
{
  int tid = blockIdx.x * blockDim.x + threadIdx.x;
  int nth = gridDim.x * blockDim.x;
  for (int m = 0; m < 2; ++m){
    const float* W0 = m ? icW0 : dpW0;
    const float* Wh = m ? icWh : dpWh;
    const float* b0 = m ? icb0 : dpb0;
    const float* bh = m ? icbh : dpbh;
    const float* Wo = m ? icWo : dpWo;
    const float* bo = m ? icbo : dpbo;
    const int indim = m ? 5 : 6;
    unsigned char* base = ws + m * MLP_BYTES;

    f16* dstF0 = (f16*)(base + FRAG0_OFF);
    for (int idx = tid; idx < 2048; idx += nth){
      int e    = idx & 7;
      int lane = (idx >> 3) & 63;
      int jt   = idx >> 9;
      int j = 32*jt + (lane & 31);
      int k = 8*(lane >> 5) + e;
      float v = (k < indim) ? W0[k*128 + j] * C2LOG2E : 0.0f;
      dstF0[idx] = (f16)v;
    }
    f16* dstFH = (f16*)(base + FRAGH_OFF);
    for (int idx = tid; idx < 3*16384; idx += nth){
      int layer = idx / 16384;
      int q     = idx & 16383;
      int e    = q & 7;
      int lane = (q >> 3) & 63;
      int f    = q >> 9;            // f = jt*8 + s
      int jt = f >> 3, s = f & 7;
      int j = 32*jt + (lane & 31);
      int k = 16*s + 8*(lane >> 5) + e;
      int row = (k & ~12) | ((k & 4) << 1) | ((k & 8) >> 1); // sigma: swap bits 2,3
      float v = Wh[(layer*128 + row)*128 + j] * C2LOG2E;
      dstFH[idx] = (f16)v;
    }
    float* dstB = (float*)(base + BIAS_OFF);
    for (int idx = tid; idx < 512; idx += nth)
      dstB[idx] = ((idx < 128) ? b0[idx] : bh[idx - 128]) * C2LOG2E;
    float* dstW = (float*)(base + WO_OFF);
    for (int idx = tid; idx < 128; idx += nth) dstW[idx] = Wo[idx];
    if (tid == 0) dstW[128] = bo[0];
  }
}

// ---------------- main fused kernel ----------------
__device__ __forceinline__ f32x16 load_bias16(const float* bp){
  float4 q0 = *(const float4*)(bp +  0);
  float4 q1 = *(const float4*)(bp +  8);
  float4 q2 = *(const float4*)(bp + 16);
  float4 q3 = *(const float4*)(bp + 24);
  f32x16 a;
  a[0]=q0.x;  a[1]=q0.y;  a[2]=q0.z;  a[3]=q0.w;
  a[4]=q1.x;  a[5]=q1.y;  a[6]=q1.z;  a[7]=q1.w;
  a[8]=q2.x;  a[9]=q2.y;  a[10]=q2.z; a[11]=q2.w;
  a[12]=q3.x; a[13]=q3.y; a[14]=q3.z; a[15]=q3.w;
  return a;
}

// 512 blocks x 512 threads (8 waves x one 32-pt tile; acc = 4 x f32x16 = 64
// regs -> r11-proven ~104 VGPR inner loop). LDS 70.6KB: F0 + hidden layer 0
// RESIDENT + bias/Wo + two 16KB stream buffers for hidden layers 1,2.
// 2 blocks/CU (141KB) = 16 waves/CU — double r6/r11's effective residency.
// 4 barriers per chain; every stage overlaps a long compute window.
__global__ __launch_bounds__(512, 2) void node_main(
    const float* __restrict__ tx,
    const unsigned char* __restrict__ ws,
    float* __restrict__ out)
{
  __shared__ __align__(16) unsigned char sF0[FRAG0_BYTES];   // 4KB input frags
  __shared__ __align__(16) unsigned char sL1[HLAYER_BYTES];  // 32KB resident Wh0
  __shared__ __align__(16) unsigned char sHL[2 * 16384];     // stream dbuf Wh1/Wh2
  __shared__ __align__(16) float sBias[512];
  __shared__ __align__(16) float sWo[136];

  const int tid  = threadIdx.x;
  const int wave = tid >> 6;
  const int lane = tid & 63;
  const int c    = lane & 31;
  const int hi   = lane >> 5;
  const int gp   = blockIdx.x * 256 + wave * 32 + c;

  // stage one half (16KB, s-slots half*4..half*4+3 of all jt) of Wh layer L
  auto stage_half = [&](const unsigned char* mb, int L, int half, int b){
    const unsigned char* src = mb + FRAGH_OFF + L*HLAYER_BYTES + half*4096;
    unsigned char* dst = sHL + b*16384;
    #pragma unroll
    for (int k = 0; k < 2; ++k){          // 16 chunks over 8 waves
      int ch = wave + 8*k;
      gl_lds16(src + (ch>>2)*8192 + (ch&3)*1024 + lane*16, dst + ch*1024);
    }
  };
  // per-MLP entry: F0 + resident L1(=Wh0) + bias + Wo + full Wh1 into b0,b1
  auto stage_entry = [&](const unsigned char* mb){
    if (wave < 4)
      gl_lds16(mb + FRAG0_OFF + wave*1024 + lane*16, sF0 + wave*1024);
    #pragma unroll
    for (int k = 0; k < 4; ++k){          // 32 chunks over 8 waves
      int ch = wave + 8*k;
      gl_lds16(mb + FRAGH_OFF + ch*1024 + lane*16, sL1 + ch*1024);
    }
    for (int i = tid; i < 128; i += 512)
      ((uint4*)sBias)[i] = ((const uint4*)(mb + BIAS_OFF))[i];
    for (int i = tid; i < 33; i += 512)
      ((uint4*)sWo)[i] = ((const uint4*)(mb + WO_OFF))[i];
    stage_half(mb, 1, 0, 0);
    stage_half(mb, 1, 1, 1);
  };

  stage_entry(ws);                 // dp entry (async; visible after first barrier)

  // ---- features ----
  float4 cc = ((const float4*)tx)[gp];
  float x = cc.y, y = cc.z, z = cc.w;
  float xy = x*x + y*y;
  float r    = sqrtf(xy + z*z + 1e-8f);
  float rho  = sqrtf(xy + 1e-8f);
  float rin  = __builtin_amdgcn_rcpf(r);
  float rhin = __builtin_amdgcn_rcpf(rho);
  float u    = r * __builtin_amdgcn_rcpf(1.0f + r);
  float cth  = z * rin;
  float sth  = rho * rin;
  float cph  = x * rhin;
  float sph  = y * rhin;
  float th   = 0.5f * cc.x;        // a = t/2 (t0 = 0)

  __syncthreads();                 // entry staging visible

  float vsum = 0.0f;
  f32x16 acc[4];
  union { f16x8 v; unsigned uu[4]; } bf[8];

  auto pack_bf = [&](){
    #pragma unroll
    for (int jt = 0; jt < 4; ++jt)
      #pragma unroll
      for (int cq = 0; cq < 2; ++cq)
        #pragma unroll
        for (int e = 0; e < 4; ++e){
          float t0 = tanh2(acc[jt][8*cq + 2*e]);
          float t1 = tanh2(acc[jt][8*cq + 2*e + 1]);
          auto pk = __builtin_amdgcn_cvt_pkrtz(t0, t1);
          bf[2*jt + cq].uu[e] = __builtin_bit_cast(unsigned, pk);
        }
  };

  #pragma unroll 1
  for (int chain = 0; chain < 4; ++chain){   // 0,1,2 = dp GL nodes; 3 = ic
    const unsigned char* mb = ws + (chain == 3 ? MLP_BYTES : 0);
    if (chain == 3) __syncthreads();         // ic entry (staged at chain-2 tail) visible

    // ---- input B-frag (k-slot = feature index; hi half = zero pad) ----
    f16x8 b0f;
    #pragma unroll
    for (int e = 0; e < 8; ++e) b0f[e] = (f16)0.0f;
    if (hi == 0){
      if (chain == 3){
        b0f[0]=(f16)u;   b0f[1]=(f16)cth; b0f[2]=(f16)sth;
        b0f[3]=(f16)cph; b0f[4]=(f16)sph;
      } else {
        const float gn = (chain == 0) ? -0.7745966692414834f :
                         (chain == 2) ?  0.7745966692414834f : 0.0f;
        float ts = th * (1.0f + gn);
        b0f[0]=(f16)ts;  b0f[1]=(f16)u;   b0f[2]=(f16)cth;
        b0f[3]=(f16)sth; b0f[4]=(f16)cph; b0f[5]=(f16)sph;
      }
    }

    // ---- input layer (bias C-in) + pack ----
    {
      const f16x8* fr = (const f16x8*)sF0;
      #pragma unroll
      for (int jt = 0; jt < 4; ++jt)
        acc[jt] = __builtin_amdgcn_mfma_f32_32x32x16_f16(
                    fr[jt*64 + lane], b0f,
                    load_bias16(&sBias[32*jt + 4*hi]), 0,0,0);
    }
    pack_bf();

    // ---- hidden layer 0 from resident sL1 ----
    {
      const f16x8* fh = (const f16x8*)sL1;
      #pragma unroll
      for (int jt = 0; jt < 4; ++jt){
        f32x16 t = load_bias16(&sBias[128 + 32*jt + 4*hi]);
        #pragma unroll
        for (int s = 0; s < 8; ++s)
          t = __builtin_amdgcn_mfma_f32_32x32x16_f16(
                fh[(jt*8 + s)*64 + lane], bf[s].v, t, 0,0,0);
        acc[jt] = t;
      }
    }
    pack_bf();

    __syncthreads();               // A: Wh1 (b0,b1) visible
    // ---- hidden layer 1 from stream buffers ----
    {
      const f16x8* f0 = (const f16x8*)(sHL);
      const f16x8* f1 = (const f16x8*)(sHL + 16384);
      #pragma unroll
      for (int jt = 0; jt < 4; ++jt){
        f32x16 t = load_bias16(&sBias[256 + 32*jt + 4*hi]);
        #pragma unroll
        for (int s2 = 0; s2 < 4; ++s2)
          t = __builtin_amdgcn_mfma_f32_32x32x16_f16(
                f0[(jt*4 + s2)*64 + lane], bf[s2].v, t, 0,0,0);
        #pragma unroll
        for (int s2 = 0; s2 < 4; ++s2)
          t = __builtin_amdgcn_mfma_f32_32x32x16_f16(
                f1[(jt*4 + s2)*64 + lane], bf[4 + s2].v, t, 0,0,0);
        acc[jt] = t;
      }
    }
    __syncthreads();               // B: b0,b1 readers done
    stage_half(mb, 2, 0, 0);       // Wh2 -> b0,b1 (overlaps pack below)
    stage_half(mb, 2, 1, 1);
    pack_bf();
    __syncthreads();               // C: Wh2 visible
    // ---- hidden layer 2 from stream buffers ----
    {
      const f16x8* f0 = (const f16x8*)(sHL);
      const f16x8* f1 = (const f16x8*)(sHL + 16384);
      #pragma unroll
      for (int jt = 0; jt < 4; ++jt){
        f32x16 t = load_bias16(&sBias[384 + 32*jt + 4*hi]);
        #pragma unroll
        for (int s2 = 0; s2 < 4; ++s2)
          t = __builtin_amdgcn_mfma_f32_32x32x16_f16(
                f0[(jt*4 + s2)*64 + lane], bf[s2].v, t, 0,0,0);
        #pragma unroll
        for (int s2 = 0; s2 < 4; ++s2)
          t = __builtin_amdgcn_mfma_f32_32x32x16_f16(
                f1[(jt*4 + s2)*64 + lane], bf[4 + s2].v, t, 0,0,0);
        acc[jt] = t;
      }
    }

    // ---- output layer ----
    {
      float v = 0.0f;
      #pragma unroll
      for (int jt = 0; jt < 4; ++jt){
        const float* wp = &sWo[32*jt + 4*hi];
        float4 q0 = *(const float4*)(wp +  0);
        float4 q1 = *(const float4*)(wp +  8);
        float4 q2 = *(const float4*)(wp + 16);
        float4 q3 = *(const float4*)(wp + 24);
        f32x16 A = acc[jt];
        v += tanh2(A[0])*q0.x  + tanh2(A[1])*q0.y
           + tanh2(A[2])*q0.z  + tanh2(A[3])*q0.w
           + tanh2(A[4])*q1.x  + tanh2(A[5])*q1.y
           + tanh2(A[6])*q1.z  + tanh2(A[7])*q1.w
           + tanh2(A[8])*q2.x  + tanh2(A[9])*q2.y
           + tanh2(A[10])*q2.z + tanh2(A[11])*q2.w
           + tanh2(A[12])*q3.x + tanh2(A[13])*q3.y
           + tanh2(A[14])*q3.z + tanh2(A[15])*q3.w;
      }
      v += __shfl_xor(v, 32);      // combine the two row-halves
      v += sWo[128];               // bo
      if (chain == 3) vsum += v;
      else {
        const float wq = (chain == 1) ? 0.8888888888888889f
                                      : 0.5555555555555556f;
        vsum = __builtin_fmaf(th * wq, v, vsum);
      }
    }

    __syncthreads();               // D: b0,b1 free; smalls free at chain 2
    if (chain < 2){                // next dp chain: restream Wh1
      stage_half(ws, 1, 0, 0);
      stage_half(ws, 1, 1, 1);
    } else if (chain == 2){        // stage full ic entry
      stage_entry(ws + MLP_BYTES);
    }
  }

  if (hi == 0) out[gp] = vsum;
}

extern "C" void kernel_launch(void* const* d_in, const int* in_sizes, int n_in,
                              void* d_out, int out_size, void* d_ws, size_t ws_size,
                              hipStream_t stream)
{
  const float* tx = (const float*)d_in[0];
  pack_weights<<<64, 256, 0, stream>>>(
      (const float*)d_in[1],  (const float*)d_in[2],  (const float*)d_in[3],
      (const float*)d_in[4],  (const float*)d_in[5],  (const float*)d_in[6],
      (const float*)d_in[7],  (const float*)d_in[8],  (const float*)d_in[9],
      (const float*)d_in[10], (const float*)d_in[11], (const float*)d_in[12],
      (unsigned char*)d_ws);
  node_main<<<NPTS/256, 512, 0, stream>>>(tx, (const unsigned char*)d_ws, (float*)d_out);
}